// Round 12
// baseline (125.480 us; speedup 1.0000x reference)
//
#include <hip/hip_runtime.h>
#include <stdint.h>

// ============================================================================
// SpikingUnifiedCoreFlow: 4-layer LIF chain, T=32, exact fixed-point via i8.
//
// R17: de-convoy. R12 PMC + pipe arithmetic shows LDS(28.6k cyc) + MFMA
// (18.7k cyc) per CU/layer ~= measured 22us ONLY if the pipes serialize:
// barriers lock all 16 waves into the same phase, so the CU alternates
// LDS-burst / MFMA-burst chip-wide. Every traffic/conflict/barrier-count
// change was neutral because none broke the lockstep.
// Fix: ELIMINATE LDS + barriers entirely. B fragments load global->VGPR
// from a FRAGMENT-ORDERED plane layout (each wave-load = contiguous 1KB,
// perfectly coalesced). Each wave free-runs: 3-bank half-chunk register
// pipeline (B[3][2][4] = 96 VGPR, 2-group prefetch depth ~600cyc > L2
// latency), compiler-counted vmcnt, no cross-wave deps. 4x mw duplication
// served by L1 (32KB chunk working set = L1-resident).
// Plane layout per (layer,nTile): [c 0..7][s 0..3][ks 0..3][row 0..63 via
// rq,rw][hi][16B] -> frag addr = nw*1024 + lr*32 + hi*16 + s*8192 + ks*2048
// + c*32768. Epilogue (shfl LIF), digit co-scheduling tail, XCD mapping,
// encode: unchanged from R14b. VGPR ~210, __launch_bounds__(512,2).
// Workspace: planes 16MB @0 | Amask0 512KB @16777216 | Amask1 @17301504
// ============================================================================

typedef __attribute__((ext_vector_type(4)))  int   i32x4;
typedef __attribute__((ext_vector_type(16))) int   i32x16;
typedef __attribute__((ext_vector_type(4)))  float f32x4;

#define SCALE_F 4294967296.0f   // 2^32
#define NSL 4

// 16 bits -> 16 i8 bytes (0/1): nibble spread, no carries (disjoint shifts)
__device__ __forceinline__ i32x4 expand16(unsigned int f) {
    i32x4 r;
    #pragma unroll
    for (int d = 0; d < 4; ++d)
        r[d] = (int)((((f >> (4 * d)) & 0xFu) * 0x00204081u) & 0x01010101u);
    return r;
}

// digit build straight into the fragment-ordered layout.
// gtid in [0, 262144): bits [nT 4][c 3][ks 2][rq 1][rw 5][hi 1][b2 2].
// weight (n,k): n = nT*64+rq*32+rw ; k = c*128+ks*32+hi*16+b2*4 (+0..3).
__device__ __forceinline__ void digits_frag(const float* __restrict__ w,
                                            signed char* __restrict__ planes,
                                            int layer, int gtid) {
    const int b2 = gtid & 3;
    const int hi = (gtid >> 2) & 1;
    const int rw = (gtid >> 3) & 31;
    const int rq = (gtid >> 8) & 1;
    const int ks = (gtid >> 9) & 3;
    const int c  = (gtid >> 11) & 7;
    const int nT = gtid >> 14;
    const int n  = nT * 64 + rq * 32 + rw;
    const int k  = c * 128 + ks * 32 + hi * 16 + b2 * 4;
    f32x4 wv = *reinterpret_cast<const f32x4*>(
            w + ((size_t)layer << 20) + (size_t)n * 1024 + k);
    long long qv[4];
    #pragma unroll
    for (int i = 0; i < 4; ++i) qv[i] = llrintf(wv[i] * SCALE_F);  // exact
    const size_t base = ((size_t)layer << 22) + ((size_t)nT << 18)
                      + (size_t)c * 32768 + ks * 2048 + rq * 1024
                      + rw * 32 + hi * 16 + b2 * 4;
    #pragma unroll
    for (int s = 0; s < NSL; ++s) {
        uint32_t pack = 0;
        #pragma unroll
        for (int i = 0; i < 4; ++i) {
            int d = (int)(signed char)((unsigned char)(qv[i] & 255));
            qv[i] = (qv[i] - d) >> 8;
            pack |= ((uint32_t)(unsigned char)d) << (8 * i);
        }
        *reinterpret_cast<uint32_t*>(planes + base + (size_t)s * 8192) = pack;
    }
}

// ------------------------------------------------------------ prep ----------
// blocks 0..1023: layer-0 digits (fragment layout); 1024..1535: encode.
__global__ void k_prep(const float* __restrict__ x, const float* __restrict__ w,
                       uint32_t* __restrict__ Am, signed char* __restrict__ planes) {
    if (blockIdx.x < 1024) {
        digits_frag(w, planes, 0, blockIdx.x * 256 + threadIdx.x);
    } else {
        // ---- encode+transpose: 2048 waves ----
        const int wid  = ((blockIdx.x - 1024) * 256 + threadIdx.x) >> 6;
        const int lane = threadIdx.x & 63;
        const int b = wid >> 4, kc = wid & 15;
        float v = x[b * 1024 + kc * 64 + lane];
        int N = (int)rintf(v * 32.0f);                 // jnp.round = half-to-even
        uint32_t bits = 0;
        if (N >= 32) {
            bits = 0xFFFFFFFFu;
        } else if (N > 0) {
            float spacing = 32.0f / (float)N;
            #pragma unroll
            for (int t = 0; t < 32; ++t) {
                float fm = fmodf((float)t, spacing);   // exact in IEEE
                if (fm < 1.0f) bits |= (1u << t);
            }
        }
        uint32_t cap = 0;
        #pragma unroll
        for (int t = 0; t < 32; ++t) {
            unsigned long long bal = __ballot((bits >> t) & 1u);
            if (lane == t)      cap = (uint32_t)bal;          // lanes 0..31: lo
            if (lane == t + 32) cap = (uint32_t)(bal >> 32);  // lanes 32..63: hi
        }
        const int t = lane & 31, ww = lane >> 5;
        Am[(size_t)(b * 32 + t) * 32 + kc * 2 + ww] = cap;
    }
}

// ----------------------------------------------------------------- fused ----
// Barrier-free, LDS-free. Each wave: A bitmasks from global (tiny), B
// fragments global->VGPR via 3-bank half-chunk pipeline, 16 MFMA/chunk.
__global__ __launch_bounds__(512, 2) void k_fused(
        const uint32_t* __restrict__ Am,
        signed char* __restrict__ planes,  // non-const: writes dlayer digits
        const float* __restrict__ th,
        const float* __restrict__ w,
        uint32_t* __restrict__ AmNext,     // null on last layer
        float* __restrict__ out,           // null except last layer
        int layer, int dlayer) {
    const int tid  = threadIdx.x;
    const int lane = tid & 63;
    const int wave = tid >> 6;             // 0..7
    const int mw   = wave >> 1;            // 0..3 : 32-row batch tile
    const int nw   = wave & 1;             // 0..1 : 32-col half
    const int lr   = lane & 31;
    const int hi   = lane >> 5;

    // bijective XCD mapping: each XCD owns 2 n-panels (512KB B, L2-resident)
    const int xc = blockIdx.x & 7, q = blockIdx.x >> 3;
    const int nTile = xc * 2 + (q & 1);    // 0..15
    const int mTile = q >> 1;              // 0..31
    const int mBase = mTile * 128, nBase = nTile * 64;

    // per-thread fragment base pointers fb[s][h]; frag (c, ks=h*2+kp) at
    // fb[s][h] + c*32768 + kp*2048. Wave-load = contiguous 1KB (coalesced).
    const signed char* fb[NSL][2];
    {
        const signed char* pb = planes + ((size_t)layer << 22)
                              + ((size_t)nTile << 18)
                              + nw * 1024 + lr * 32 + hi * 16;
        #pragma unroll
        for (int s = 0; s < NSL; ++s)
            #pragma unroll
            for (int h = 0; h < 2; ++h)
                fb[s][h] = pb + s * 8192 + h * 4096;
    }
    // A bitmask row pointer (u32 words; row stride 32 words = 128B)
    const uint32_t* aRow = Am + (size_t)(mBase + mw * 32 + lr) * 32;

    i32x16 acc[NSL];
    #pragma unroll
    for (int s = 0; s < NSL; ++s)
        #pragma unroll
        for (int r = 0; r < 16; ++r) acc[s][r] = 0;

    i32x4 B[3][2][NSL];                    // [bank][kp][s] = 96 VGPR
    i32x4 amr[2];                          // per-chunk A bits, ping-pong

    auto LOADG = [&](int bank, int c, int h) {
        #pragma unroll
        for (int kp = 0; kp < 2; ++kp)
            #pragma unroll
            for (int s = 0; s < NSL; ++s)
                B[bank][kp][s] = *reinterpret_cast<const i32x4*>(
                        fb[s][h] + (size_t)c * 32768 + kp * 2048);
    };

    // prologue: 2 groups in flight + first A-mask
    LOADG(0, 0, 0);
    amr[0] = *reinterpret_cast<const i32x4*>(aRow);
    LOADG(1, 0, 1);

    // 16 half-chunk groups; bank rotation g%3 (folds under full unroll)
    #pragma unroll
    for (int g = 0; g < 16; ++g) {
        const int c = g >> 1, h = g & 1, bank = g % 3;
        if (g + 2 < 16) LOADG((g + 2) % 3, (g + 2) >> 1, (g + 2) & 1);
        if (h == 0 && c + 1 < 8)           // issue 2 groups early (~600cyc)
            amr[(c + 1) & 1] = *reinterpret_cast<const i32x4*>(aRow + (c + 1) * 4);

        __builtin_amdgcn_s_setprio(1);
        #pragma unroll
        for (int kp = 0; kp < 2; ++kp) {
            i32x4 af = expand16(
                (((unsigned)amr[c & 1][h * 2 + kp]) >> (16 * hi)) & 0xFFFFu);
            #pragma unroll
            for (int s = 0; s < NSL; ++s)
                acc[s] = __builtin_amdgcn_mfma_i32_32x32x32_i8(
                        af, B[bank][kp][s], acc[s], 0, 0, 0);
        }
        __builtin_amdgcn_s_setprio(0);
    }

    // epilogue: combine slices -> int64, swap halves, LIF recurrence on ALL
    // lanes (hi halves compute identical bits), ballot-transpose to next mask.
    // C/D 32x32: col=lane&31, row(t) = (r&3) + 8*(r>>2) + 4*hi  [m74/m101]
    const long long TH = llrintf(th[layer] * SCALE_F);
    const int batch = mTile * 4 + mw;
    uint32_t bits = 0;
    long long mmem = 0;
    #pragma unroll
    for (int half = 0; half < 2; ++half) {
        long long own[8], par[8];
        #pragma unroll
        for (int r = 0; r < 8; ++r) {
            long long v = 0;
            #pragma unroll
            for (int s = 0; s < NSL; ++s)
                v += ((long long)acc[s][half * 8 + r]) << (8 * s);
            own[r] = v;
        }
        #pragma unroll
        for (int r = 0; r < 8; ++r) {
            int plo = __shfl((int)(uint32_t)own[r], lane ^ 32, 64);
            int phi = __shfl((int)(own[r] >> 32), lane ^ 32, 64);
            par[r] = ((long long)phi << 32) | (uint32_t)plo;
        }
        #pragma unroll
        for (int tq = 0; tq < 16; ++tq) {   // t = half*16 + tq
            const int idx = (tq >> 3) * 4 + (tq & 3);
            const int usePar = ((tq >> 2) & 1) ^ hi;
            long long v = usePar ? par[idx] : own[idx];
            mmem += v;
            if (mmem > TH) { mmem -= TH; bits |= (1u << (half * 16 + tq)); }
        }
    }

    if (AmNext) {
        uint32_t cap = 0;
        #pragma unroll
        for (int t = 0; t < 32; ++t) {
            unsigned long long bal = __ballot((bits >> t) & 1u);
            if (lane == t) cap = (uint32_t)bal;   // lo32 = cols of this nw half
        }
        if (hi == 0)
            AmNext[(size_t)(batch * 32 + lr) * 32 + nTile * 2 + nw] = cap;
    } else if (hi == 0) {
        out[batch * 1024 + nBase + nw * 32 + lr] = (float)__popc(bits) * 0.03125f;
    }

    // co-scheduled digit build for the NEXT layer (acc dead; rides the
    // block-retirement drain). 512 blocks x 512 thr = 262144 units = exact.
    if (dlayer < 4)
        digits_frag(w, planes, dlayer, blockIdx.x * 512 + tid);
}

// ---------------------------------------------------------------- launch ----
extern "C" void kernel_launch(void* const* d_in, const int* in_sizes, int n_in,
                              void* d_out, int out_size, void* d_ws, size_t ws_size,
                              hipStream_t stream) {
    const float* x  = (const float*)d_in[0];
    const float* w  = (const float*)d_in[1];
    const float* th = (const float*)d_in[2];
    float* out = (float*)d_out;
    char* ws = (char*)d_ws;

    signed char* planes = (signed char*)(ws);                 // 16 MB
    uint32_t*    Am0    = (uint32_t*)(ws + 16777216);         // 512 KB
    uint32_t*    Am1    = (uint32_t*)(ws + 17301504);         // 512 KB

    k_prep<<<1536, 256, 0, stream>>>(x, w, Am0, planes);

    uint32_t* Ain = Am0;
    uint32_t* Anx = Am1;
    for (int l = 0; l < 4; ++l) {
        k_fused<<<512, 512, 0, stream>>>(Ain, planes, th, w,
                                         (l < 3) ? Anx : nullptr,
                                         (l == 3) ? out : nullptr,
                                         l, l + 1);
        uint32_t* tmp = Ain; Ain = Anx; Anx = tmp;
    }
}

// Round 13
// 102.420 us; speedup vs baseline: 1.2252x; 1.2252x over previous
//
#include <hip/hip_runtime.h>
#include <stdint.h>

// ============================================================================
// SpikingUnifiedCoreFlow: 4-layer LIF chain, T=32, exact fixed-point via i8.
//
// R18: REVERT to R14b (harness-verified best, 103.3us, absmax 0). R17's
// LDS-free global->VGPR path regressed (125.5): in-order vmcnt serializes
// load groups, L1 pays the 4x mw duplication LDS served free. Ledger after
// 7 structural k_fused variants: 103-106us band is invariant to LDS
// traffic, conflicts, occupancy, barrier count, pacing, and data path.
// Only work-reduction (R7 slices 5->4) and overhead-hiding (R14b digit
// co-scheduling) ever moved the number; both exhausted. Persistent +
// per-mTile sync rejected on coherence arithmetic (sc1 plane traffic
// would forfeit ~8us/layer of L2 B-panel reuse > ~6-8us of launch gaps).
//
// Structure: k_prep = encode + layer-0 digits; k_fused x4 = R10's proven
// 2-phase pacing (P1 vmcnt(2) {issue H0/A/H1 of c+1}, P2 vmcnt(5), tail 0)
// + LIF epilogue + co-scheduled layer-(l+1) digit build riding the
// block-retirement drain.
// Workspace: planes 16MB @0 | Amask0 512KB @16777216 | Amask1 @17301504
// ============================================================================

typedef __attribute__((ext_vector_type(4)))  int   i32x4;
typedef __attribute__((ext_vector_type(16))) int   i32x16;
typedef __attribute__((ext_vector_type(4)))  float f32x4;

#define SCALE_F 4294967296.0f   // 2^32
#define NSL 4

__device__ __forceinline__ void gload16(const void* g, void* l) {
    __builtin_amdgcn_global_load_lds(
        (const __attribute__((address_space(1))) void*)g,
        (__attribute__((address_space(3))) void*)l, 16, 0, 0);
}

// 16 bits -> 16 i8 bytes (0/1): nibble spread, no carries (disjoint shifts)
__device__ __forceinline__ i32x4 expand16(unsigned int f) {
    i32x4 r;
    #pragma unroll
    for (int d = 0; d < 4; ++d)
        r[d] = (int)((((f >> (4 * d)) & 0xFu) * 0x00204081u) & 0x01010101u);
    return r;
}

// digit decomposition of 4 consecutive weights -> 4 planes
__device__ __forceinline__ void digits4(const float* __restrict__ w,
                                        signed char* __restrict__ planes,
                                        int layer, int rest4) {
    f32x4 wv = *reinterpret_cast<const f32x4*>(w + ((size_t)layer << 20) + rest4);
    long long q[4];
    #pragma unroll
    for (int i = 0; i < 4; ++i) q[i] = llrintf(wv[i] * SCALE_F);  // exact
    #pragma unroll
    for (int s = 0; s < NSL; ++s) {
        uint32_t pack = 0;
        #pragma unroll
        for (int i = 0; i < 4; ++i) {
            int d = (int)(signed char)((unsigned char)(q[i] & 255));
            q[i] = (q[i] - d) >> 8;
            pack |= ((uint32_t)(unsigned char)d) << (8 * i);
        }
        *reinterpret_cast<uint32_t*>(planes + (((size_t)(layer * NSL + s)) << 20) + rest4) = pack;
    }
}

// ------------------------------------------------------------ prep ----------
// blocks 0..1023: layer-0 digit decomposition; blocks 1024..1535: encode.
__global__ void k_prep(const float* __restrict__ x, const float* __restrict__ w,
                       uint32_t* __restrict__ Am, signed char* __restrict__ planes) {
    if (blockIdx.x < 1024) {
        // ---- digits, layer 0 only: 256K threads, 4 weights each ----
        int tid = blockIdx.x * 256 + threadIdx.x;      // 0..262143
        digits4(w, planes, 0, tid << 2);
    } else {
        // ---- encode+transpose: 2048 waves ----
        const int wid  = ((blockIdx.x - 1024) * 256 + threadIdx.x) >> 6;
        const int lane = threadIdx.x & 63;
        const int b = wid >> 4, kc = wid & 15;
        float v = x[b * 1024 + kc * 64 + lane];
        int N = (int)rintf(v * 32.0f);                 // jnp.round = half-to-even
        uint32_t bits = 0;
        if (N >= 32) {
            bits = 0xFFFFFFFFu;
        } else if (N > 0) {
            float spacing = 32.0f / (float)N;
            #pragma unroll
            for (int t = 0; t < 32; ++t) {
                float fm = fmodf((float)t, spacing);   // exact in IEEE
                if (fm < 1.0f) bits |= (1u << t);
            }
        }
        uint32_t cap = 0;
        #pragma unroll
        for (int t = 0; t < 32; ++t) {
            unsigned long long bal = __ballot((bits >> t) & 1u);
            if (lane == t)      cap = (uint32_t)bal;          // lanes 0..31: lo
            if (lane == t + 32) cap = (uint32_t)(bal >> 32);  // lanes 32..63: hi
        }
        const int t = lane & 31, ww = lane >> 5;
        Am[(size_t)(b * 32 + t) * 32 + kc * 2 + ww] = cap;
    }
}

// ----------------------------------------------------------------- fused ----
// LDS/buf (32KB): slice s @ s*8192 : [row 0..63][8 slots][16B]; physical slot
// q holds GLOBAL k-granule q ^ (row&7) (source-pre-swizzle).
__global__ __launch_bounds__(512, 4) void k_fused(
        const uint32_t* __restrict__ Am,
        signed char* __restrict__ planes,  // non-const: writes dlayer digits
        const float* __restrict__ th,
        const float* __restrict__ w,
        uint32_t* __restrict__ AmNext,     // null on last layer
        float* __restrict__ out,           // null except last layer
        int layer, int dlayer) {
    __shared__ alignas(16) signed char lds[2][32768];

    const int tid  = threadIdx.x;
    const int lane = tid & 63;
    const int wave = tid >> 6;             // 0..7
    const int mw   = wave >> 1;            // 0..3 : 32-row batch tile
    const int nw   = wave & 1;             // 0..1 : 32-col half
    const int lr   = lane & 31;
    const int hi   = lane >> 5;

    // bijective XCD mapping: each XCD owns 2 n-panels (512KB B, L2-resident)
    const int xc = blockIdx.x & 7, q = blockIdx.x >> 3;
    const int nTile = xc * 2 + (q & 1);    // 0..15
    const int mTile = q >> 1;              // 0..31
    const int mBase = mTile * 128, nBase = nTile * 64;

    // B staging sources: 4 units(16B)/thread/chunk, source-pre-swizzled
    const signed char* srcB[NSL];
    {
        const int r0 = tid >> 3, qs = tid & 7;
        const int sw0 = (qs ^ (r0 & 7)) * 16;
        #pragma unroll
        for (int s = 0; s < NSL; ++s)
            srcB[s] = planes + (((size_t)(layer * NSL + s)) << 20)
                    + (size_t)(nBase + r0) * 1024 + sw0;
    }
    // A bitmask row pointer (u32 words; row stride 32 words = 128B)
    const uint32_t* aRow = Am + (size_t)(mBase + mw * 32 + lr) * 32;

    // per-thread B read addresses (dynamic part); slice base added separately
    int baddr[4];
    {
        const int brow = nw * 32 + lr;
        #pragma unroll
        for (int ks = 0; ks < 4; ++ks)
            baddr[ks] = brow * 128 + (((ks * 2 + hi) ^ (brow & 7)) * 16);
    }

    i32x16 acc[NSL];
    #pragma unroll
    for (int s = 0; s < NSL; ++s)
        #pragma unroll
        for (int r = 0; r < 16; ++r) acc[s][r] = 0;

    auto H0 = [&](int buf, int c) {        // slices 0,1 : 2 units/thread
        const int ko = c * 128;
        gload16(srcB[0] + ko, &lds[buf][0]    + tid * 16);
        gload16(srcB[1] + ko, &lds[buf][8192] + tid * 16);
    };
    auto H1 = [&](int buf, int c) {        // slices 2,3 : 2 units/thread
        const int ko = c * 128;
        gload16(srcB[2] + ko, &lds[buf][16384] + tid * 16);
        gload16(srcB[3] + ko, &lds[buf][24576] + tid * 16);
    };

    i32x4 amr[2];                          // per-chunk A bits, ping-pong
    H0(0, 0);
    amr[0] = *reinterpret_cast<const i32x4*>(aRow);
    H1(0, 0);

    #pragma unroll
    for (int c = 0; c < 8; ++c) {
        const int buf = c & 1;
        const signed char* lb = &lds[buf][0];

        // ---- phase 1: need H0(c)+A(c); H1(c)^2 stays in flight ----
        asm volatile("s_waitcnt vmcnt(2)" ::: "memory");
        __builtin_amdgcn_s_barrier();
        asm volatile("" ::: "memory");

        if (c + 1 < 8) {                   // issue ALL of chunk c+1 here:
            H0(buf ^ 1, c + 1);            // P2 becomes pure compute, and
            amr[(c + 1) & 1] = *reinterpret_cast<const i32x4*>(aRow + (c + 1) * 4);
            H1(buf ^ 1, c + 1);            // H1 gets a full phase of flight
        }

        i32x4 af[4];                       // A fragments, reused in phase 2
        __builtin_amdgcn_s_setprio(1);
        #pragma unroll
        for (int ks = 0; ks < 4; ++ks) {
            af[ks] = expand16((((unsigned)amr[c & 1][ks]) >> (16 * hi)) & 0xFFFFu);
            #pragma unroll
            for (int s = 0; s < 2; ++s) {
                i32x4 bf = *reinterpret_cast<const i32x4*>(lb + s * 8192 + baddr[ks]);
                acc[s] = __builtin_amdgcn_mfma_i32_32x32x32_i8(af[ks], bf, acc[s], 0, 0, 0);
            }
        }
        __builtin_amdgcn_s_setprio(0);

        // ---- phase 2: need H1(c); c+1's 5 loads stay in flight ----
        if (c + 1 < 8) asm volatile("s_waitcnt vmcnt(5)" ::: "memory");
        else           asm volatile("s_waitcnt vmcnt(0)" ::: "memory");
        __builtin_amdgcn_s_barrier();
        asm volatile("" ::: "memory");

        __builtin_amdgcn_s_setprio(1);
        #pragma unroll
        for (int ks = 0; ks < 4; ++ks) {
            #pragma unroll
            for (int s = 0; s < 2; ++s) {
                i32x4 bf = *reinterpret_cast<const i32x4*>(lb + (2 + s) * 8192 + baddr[ks]);
                acc[2 + s] = __builtin_amdgcn_mfma_i32_32x32x32_i8(af[ks], bf, acc[2 + s], 0, 0, 0);
            }
        }
        __builtin_amdgcn_s_setprio(0);
    }

    // epilogue: combine slices -> int64, swap halves, LIF recurrence on ALL
    // lanes (hi halves compute identical bits), ballot-transpose to next mask.
    // C/D 32x32: col=lane&31, row(t) = (r&3) + 8*(r>>2) + 4*hi  [m74/m101]
    const long long TH = llrintf(th[layer] * SCALE_F);
    const int batch = mTile * 4 + mw;
    uint32_t bits = 0;
    long long mmem = 0;
    #pragma unroll
    for (int half = 0; half < 2; ++half) {
        long long own[8], par[8];
        #pragma unroll
        for (int r = 0; r < 8; ++r) {
            long long v = 0;
            #pragma unroll
            for (int s = 0; s < NSL; ++s)
                v += ((long long)acc[s][half * 8 + r]) << (8 * s);
            own[r] = v;
        }
        #pragma unroll
        for (int r = 0; r < 8; ++r) {
            int plo = __shfl((int)(uint32_t)own[r], lane ^ 32, 64);
            int phi = __shfl((int)(own[r] >> 32), lane ^ 32, 64);
            par[r] = ((long long)phi << 32) | (uint32_t)plo;
        }
        #pragma unroll
        for (int tq = 0; tq < 16; ++tq) {   // t = half*16 + tq
            const int idx = (tq >> 3) * 4 + (tq & 3);
            const int usePar = ((tq >> 2) & 1) ^ hi;
            long long v = usePar ? par[idx] : own[idx];
            mmem += v;
            if (mmem > TH) { mmem -= TH; bits |= (1u << (half * 16 + tq)); }
        }
    }

    if (AmNext) {
        uint32_t cap = 0;
        #pragma unroll
        for (int t = 0; t < 32; ++t) {
            unsigned long long bal = __ballot((bits >> t) & 1u);
            if (lane == t) cap = (uint32_t)bal;   // lo32 = cols of this nw half
        }
        if (hi == 0)
            AmNext[(size_t)(batch * 32 + lr) * 32 + nTile * 2 + nw] = cap;
    } else if (hi == 0) {
        out[batch * 1024 + nBase + nw * 32 + lr] = (float)__popc(bits) * 0.03125f;
    }

    // co-scheduled digit build for the NEXT layer (acc dead; rides the
    // block-retirement drain). 512 blocks x 512 thr x 4 weights = 1M = exact.
    if (dlayer < 4)
        digits4(w, planes, dlayer, (blockIdx.x * 512 + tid) << 2);
}

// ---------------------------------------------------------------- launch ----
extern "C" void kernel_launch(void* const* d_in, const int* in_sizes, int n_in,
                              void* d_out, int out_size, void* d_ws, size_t ws_size,
                              hipStream_t stream) {
    const float* x  = (const float*)d_in[0];
    const float* w  = (const float*)d_in[1];
    const float* th = (const float*)d_in[2];
    float* out = (float*)d_out;
    char* ws = (char*)d_ws;

    signed char* planes = (signed char*)(ws);                 // 16 MB
    uint32_t*    Am0    = (uint32_t*)(ws + 16777216);         // 512 KB
    uint32_t*    Am1    = (uint32_t*)(ws + 17301504);         // 512 KB

    k_prep<<<1536, 256, 0, stream>>>(x, w, Am0, planes);

    uint32_t* Ain = Am0;
    uint32_t* Anx = Am1;
    for (int l = 0; l < 4; ++l) {
        k_fused<<<512, 512, 0, stream>>>(Ain, planes, th, w,
                                         (l < 3) ? Anx : nullptr,
                                         (l == 3) ? out : nullptr,
                                         l, l + 1);
        uint32_t* tmp = Ain; Ain = Anx; Anx = tmp;
    }
}